// Round 4
// baseline (110.436 us; speedup 1.0000x reference)
//
#include <hip/hip_runtime.h>

// DeformConv2D b=4,c=128,H=W=64,outc=128,KS=3,PAD=1,N=9
// out[(b,i,j),o] = sum_ck W[o][ck] * A[ck][(b,i,j)], ck = tap*128 + c, K=1152
// Stage 1: x NCHW fp32 -> x_t (b,hw,c) bf16
// Stage 2: weight -> MFMA A-fragment layout wfrag[ot][ks][lane][8] bf16
// Stage 3: per (b,i,32px): 3 tap-chunks of {bilinear stage -> LDS, 12 MFMA K-steps}
//          wave = one 16-o tile x 32 px (2 accs, shared A-frag)

typedef __bf16  v8bf16 __attribute__((ext_vector_type(8)));
typedef __bf16  bf16x2 __attribute__((ext_vector_type(2)));
typedef float   f32x4  __attribute__((ext_vector_type(4)));
typedef unsigned short ushort4v __attribute__((ext_vector_type(4)));
typedef _Float16 half4v __attribute__((ext_vector_type(4)));

#define CIN  128
#define NPT  9
#define KTOT 1152
#define OC   128
#define PX   32
#define NDESC (NPT * PX)   // 288
#define KSTEPS 36          // total K-steps of 32
#define TAPG 3             // taps per chunk
#define KSC  12            // K-steps per chunk
#define LDBc 392           // Bt row stride bf16 (784B: 16B-aligned, even bank spread)

// ---------- x NCHW fp32 -> channels-last bf16 ----------
__global__ __launch_bounds__(256) void xpose_kernel(const float* __restrict__ x,
                                                    __bf16* __restrict__ xt) {
    __shared__ float tile[64][33];
    const int bidx = blockIdx.x;            // 4 b * 64 hwt * 4 ct
    const int b   = bidx >> 8;
    const int hw0 = ((bidx >> 2) & 63) * 64;
    const int c0  = (bidx & 3) * 32;
    const int tid = threadIdx.x;
    #pragma unroll
    for (int r = 0; r < 8; ++r) {
        int c_l  = (tid >> 6) + r * 4;
        int hw_l = tid & 63;
        tile[hw_l][c_l] = x[((size_t)(b * CIN + c0 + c_l) << 12) + hw0 + hw_l];
    }
    __syncthreads();
    #pragma unroll
    for (int r = 0; r < 8; ++r) {
        int hw_l = (tid >> 5) + r * 8;
        int c_l  = tid & 31;
        xt[((size_t)(b * 4096 + hw0 + hw_l)) * CIN + c0 + c_l] = (__bf16)tile[hw_l][c_l];
    }
}

// ---------- weight -> A-fragment layout ----------
// wfrag[((ot*36+ks)*64 + lane)*8 + e] = (bf16) w[o*1152 + c*9 + tap]
//   o = ot*16 + (lane&15), k = ks*32 + (lane>>4)*8 + e, tap = k>>7, c = k&127
__global__ __launch_bounds__(256) void wfrag_kernel(const float* __restrict__ w,
                                                    __bf16* __restrict__ wfrag) {
    int t = blockIdx.x * 256 + threadIdx.x;     // [0, 8*36*64)
    if (t >= 8 * KSTEPS * 64) return;
    int lane = t & 63;
    int ks   = (t >> 6) % KSTEPS;
    int ot   = t / (KSTEPS * 64);
    int o    = ot * 16 + (lane & 15);
    v8bf16 frag;
    #pragma unroll
    for (int e = 0; e < 8; ++e) {
        int k   = ks * 32 + (lane >> 4) * 8 + e;
        int tap = k >> 7, c = k & 127;
        frag[e] = (__bf16)w[(size_t)o * KTOT + c * NPT + tap];
    }
    *(v8bf16*)(wfrag + (size_t)t * 8) = frag;
}

__global__ __launch_bounds__(512, 6) void deform_mfma_kernel(
    const float* __restrict__ x, const float* __restrict__ off,
    const float* __restrict__ w, const __bf16* __restrict__ wfrag,
    const __bf16* __restrict__ xt, float* __restrict__ out, int mode)
{
    __shared__ __align__(16) __bf16 Bt[PX][LDBc];         // 25088 B
    __shared__ __align__(8)  unsigned short sIdxP[NDESC][4];
    __shared__ __align__(8)  _Float16      sGP[NDESC][4];

    const int bidx = blockIdx.x;          // 512 = b(4) * i(64) * jh(2)
    const int b   = bidx >> 7;
    const int i   = (bidx >> 1) & 63;
    const int j0  = (bidx & 1) * PX;
    const int tid = threadIdx.x;

    // ---- Phase S: sampling geometry (d = tap*32 + p) ----
    if (tid < NDESC) {
        int k = tid >> 5, p = tid & 31;
        int j = j0 + p;
        float ox = off[(((b * 18) + 2 * k) * 64 + i) * 64 + j];
        float oy = off[(((b * 18) + 2 * k + 1) * 64 + i) * 64 + j];
        float px = (float)(i + k / 3) + ox;
        float py = (float)(j + k % 3) + oy;
        float fx = floorf(px), fy = floorf(py);
        int qltx = (int)fminf(fmaxf(fx, 0.f), 65.f);
        int qlty = (int)fminf(fmaxf(fy, 0.f), 65.f);
        int qrbx = (int)fminf(fmaxf(fx + 1.f, 0.f), 65.f);
        int qrby = (int)fminf(fmaxf(fy + 1.f, 0.f), 65.f);
        if (px < 1.f || px > 64.f) px = fx;
        if (py < 1.f || py > 64.f) py = fy;
        px = fminf(fmaxf(px, 0.f), 65.f);
        py = fminf(fmaxf(py, 0.f), 65.f);
        float wxl = 1.f + (float)qltx - px;
        float wxr = 1.f - ((float)qrbx - px);
        float wyl = 1.f + (float)qlty - py;
        float wyr = 1.f - ((float)qrby - py);
        float g[4] = { wxl * wyl, wxr * wyr, wxl * wyr, wxr * wyl };
        int qx[4] = { qltx, qrbx, qltx, qrbx };
        int qy[4] = { qlty, qrby, qrby, qlty };
        #pragma unroll
        for (int cr = 0; cr < 4; ++cr) {
            bool inb = (qx[cr] >= 1) && (qx[cr] <= 64) && (qy[cr] >= 1) && (qy[cr] <= 64);
            sIdxP[tid][cr] = inb ? (unsigned short)((qx[cr] - 1) * 64 + (qy[cr] - 1)) : 0;
            sGP[tid][cr]   = inb ? (_Float16)g[cr] : (_Float16)0.f;
        }
    }
    __syncthreads();

    const int l    = tid & 63;
    const int wv   = tid >> 6;   // 0..7 -> o-tile ot = wv
    const int quad = l >> 4;
    const int lr   = l & 15;

    f32x4 acc0 = {0.f, 0.f, 0.f, 0.f};   // px 0..15
    f32x4 acc1 = {0.f, 0.f, 0.f, 0.f};   // px 16..31

    const __bf16* xtb = xt + ((size_t)b * 4096) * CIN;
    const float*  xb  = x + ((size_t)b * CIN << 12);
    const __bf16* brow0 = &Bt[lr][quad * 8];
    const __bf16* brow1 = &Bt[16 + lr][quad * 8];

    for (int t = 0; t < 3; ++t) {
        // ---- stage chunk t: taps 3t..3t+2, wave wv handles 12 descriptors ----
        if (mode == 2) {
            #pragma unroll 4
            for (int dd = 0; dd < KSC; ++dd) {
                int dl = wv * KSC + dd;              // [0,96)
                int tap_l = dl >> 5, p = dl & 31;
                int d = t * 96 + dl;
                ushort4v id = *(const ushort4v*)&sIdxP[d][0];
                half4v   gh = *(const half4v*)&sGP[d][0];
                float s0 = 0.f, s1 = 0.f;
                #pragma unroll
                for (int cr = 0; cr < 4; ++cr) {
                    unsigned int v = *(const unsigned int*)(xtb + (size_t)id[cr] * CIN + 2 * l);
                    float c0v, c1v;
                    unsigned int lo = v << 16, hi = v & 0xffff0000u;
                    __builtin_memcpy(&c0v, &lo, 4);
                    __builtin_memcpy(&c1v, &hi, 4);
                    float gf = (float)gh[cr];
                    s0 += gf * c0v;
                    s1 += gf * c1v;
                }
                bf16x2 pr = { (__bf16)s0, (__bf16)s1 };
                *(bf16x2*)&Bt[p][tap_l * CIN + 2 * l] = pr;
            }
        } else {
            for (int dd = 0; dd < KSC; ++dd) {
                int dl = wv * KSC + dd;
                int tap_l = dl >> 5, p = dl & 31;
                int d = t * 96 + dl;
                ushort4v id = *(const ushort4v*)&sIdxP[d][0];
                half4v   gh = *(const half4v*)&sGP[d][0];
                float s0 = 0.f, s1 = 0.f;
                #pragma unroll
                for (int cr = 0; cr < 4; ++cr) {
                    float gf = (float)gh[cr];
                    s0 += gf * xb[((size_t)(2 * l) << 12) + id[cr]];
                    s1 += gf * xb[((size_t)(2 * l + 1) << 12) + id[cr]];
                }
                bf16x2 pr = { (__bf16)s0, (__bf16)s1 };
                *(bf16x2*)&Bt[p][tap_l * CIN + 2 * l] = pr;
            }
        }
        __syncthreads();

        // ---- MFMA: 12 K-steps; one shared afrag, two px-half bfrags ----
        #pragma unroll 4
        for (int ks = 0; ks < KSC; ++ks) {
            int ks_g = t * KSC + ks;
            v8bf16 bfrag0 = *(const v8bf16*)(brow0 + ks * 32);
            v8bf16 bfrag1 = *(const v8bf16*)(brow1 + ks * 32);
            v8bf16 afrag;
            if (mode >= 1) {
                afrag = *(const v8bf16*)(wfrag + (((size_t)wv * KSTEPS + ks_g) * 64 + l) * 8);
            } else {
                int o = wv * 16 + lr;
                #pragma unroll
                for (int e = 0; e < 8; ++e) {
                    int k = ks_g * 32 + quad * 8 + e;
                    int tap = k >> 7, c = k & 127;
                    afrag[e] = (__bf16)w[(size_t)o * KTOT + c * NPT + tap];
                }
            }
            acc0 = __builtin_amdgcn_mfma_f32_16x16x32_bf16(afrag, bfrag0, acc0, 0, 0, 0);
            acc1 = __builtin_amdgcn_mfma_f32_16x16x32_bf16(afrag, bfrag1, acc1, 0, 0, 0);
        }
        if (t < 2) __syncthreads();
    }

    // ---- epilogue: o = wv*16 + quad*4 + r, col j = j0 + ph*16 + lr ----
    #pragma unroll
    for (int ph = 0; ph < 2; ++ph) {
        int obase = wv * 16 + quad * 4;
        float* op = out + (((size_t)(b * OC + obase)) << 12) + (i << 6) + j0 + ph * 16 + lr;
        f32x4 a = (ph == 0) ? acc0 : acc1;
        #pragma unroll
        for (int r = 0; r < 4; ++r)
            op[(size_t)r << 12] = a[r];
    }
}

extern "C" void kernel_launch(void* const* d_in, const int* in_sizes, int n_in,
                              void* d_out, int out_size, void* d_ws, size_t ws_size,
                              hipStream_t stream) {
    const float* x   = (const float*)d_in[0];
    const float* off = (const float*)d_in[1];
    const float* w   = (const float*)d_in[2];
    float* out = (float*)d_out;

    const size_t wfrag_bytes = (size_t)OC * KTOT * sizeof(__bf16);      // 294912
    const size_t xt_bytes    = (size_t)4 * 4096 * CIN * sizeof(__bf16); // 4 MB
    int mode = 0;
    if (ws_size >= wfrag_bytes + xt_bytes) mode = 2;
    else if (ws_size >= wfrag_bytes) mode = 1;

    __bf16* wfrag = (__bf16*)d_ws;
    __bf16* xt    = (__bf16*)((char*)d_ws + wfrag_bytes);

    if (mode >= 1) {
        wfrag_kernel<<<(8 * KSTEPS * 64 + 255) / 256, 256, 0, stream>>>(w, wfrag);
    }
    if (mode == 2) {
        xpose_kernel<<<4 * 64 * 4, 256, 0, stream>>>(x, xt);
    }
    deform_mfma_kernel<<<4 * 64 * 2, 512, 0, stream>>>(x, off, w, wfrag, xt, out, mode);
}